// Round 4
// baseline (13557.446 us; speedup 1.0000x reference)
//
#include <hip/hip_runtime.h>

#define NSVC 2000
#define NPOD 8000
#define NNODE 1000
#define NTOT 11000
#define TT 32
#define FF 64
#define HH 128
#define EA 30000
#define EB 24000
#define EC 24000
#define ETOT (EA + EB + EC)
#define CHK 64
#define NCH ((NTOT + CHK - 1) / CHK)   // 172

// ---------------- agent-scope helpers (cross-XCD safe) ----------------
__device__ __forceinline__ float ld_agent(const float* p) {
    return __hip_atomic_load(p, __ATOMIC_RELAXED, __HIP_MEMORY_SCOPE_AGENT);
}
__device__ __forceinline__ void st_agent(float* p, float v) {
    __hip_atomic_store(p, v, __ATOMIC_RELAXED, __HIP_MEMORY_SCOPE_AGENT);
}
// barrier that does NOT drain vmcnt (keeps global loads/stores in flight)
__device__ __forceinline__ void bar_fast() {
    asm volatile("s_waitcnt lgkmcnt(0)" ::: "memory");
    __builtin_amdgcn_s_barrier();
}

// ---------------- merged degree counting ----------------
__global__ void k_count3(const int* __restrict__ sA, const int* __restrict__ dA,
                         const int* __restrict__ sB, const int* __restrict__ dB,
                         const int* __restrict__ sC, const int* __restrict__ dC,
                         float* ocA, float* icA, float* ocB, float* icB,
                         float* ocC, float* icC) {
    int e = blockIdx.x * 256 + threadIdx.x;
    if (e < EA) {
        atomicAdd(ocA + sA[e], 1.f); atomicAdd(icA + dA[e], 1.f);
    } else if (e < EA + EB) {
        int i = e - EA;
        atomicAdd(ocB + sB[i], 1.f); atomicAdd(icB + dB[i], 1.f);
    } else if (e < ETOT) {
        int i = e - EA - EB;
        atomicAdd(ocC + sC[i], 1.f); atomicAdd(icC + dC[i], 1.f);
    }
}

// ---------------- prefix scan (3 graphs, one block each) ----------------
__global__ void k_scan(const float* cA, int nA, int* oA,
                       const float* cB, int nB, int* oB,
                       const float* cC, int nC, int* oC) {
    const float* c; int n; int* o;
    if (blockIdx.x == 0)      { c = cA; n = nA; o = oA; }
    else if (blockIdx.x == 1) { c = cB; n = nB; o = oB; }
    else                      { c = cC; n = nC; o = oC; }
    __shared__ int s[256];
    __shared__ int carry;
    int tid = threadIdx.x;
    if (tid == 0) { carry = 0; o[0] = 0; }
    __syncthreads();
    for (int base = 0; base < n; base += 256) {
        int idx = base + tid;
        int v = (idx < n) ? (int)c[idx] : 0;
        s[tid] = v;
        __syncthreads();
        for (int d = 1; d < 256; d <<= 1) {
            int t = (tid >= d) ? s[tid - d] : 0;
            __syncthreads();
            s[tid] += t;
            __syncthreads();
        }
        if (idx < n) o[idx + 1] = carry + s[tid];
        __syncthreads();
        if (tid == 255) carry += s[255];
        __syncthreads();
    }
}

// ---------------- merged CSR scatter ----------------
__global__ void k_scatter3(const int* __restrict__ sA, const int* __restrict__ dA,
                           const int* __restrict__ sB, const int* __restrict__ dB,
                           const int* __restrict__ sC, const int* __restrict__ dC,
                           const int* offA, int* curA, int* csrA,
                           const int* offB, int* curB, int* csrB,
                           const int* offC, int* curC, int* csrC) {
    int e = blockIdx.x * 256 + threadIdx.x;
    if (e < EA) {
        int d = dA[e]; int p = atomicAdd(curA + d, 1); csrA[offA[d] + p] = sA[e];
    } else if (e < EA + EB) {
        int i = e - EA;
        int d = dB[i]; int p = atomicAdd(curB + d, 1); csrB[offB[d] + p] = sB[i];
    } else if (e < ETOT) {
        int i = e - EA - EB;
        int d = dC[i]; int p = atomicAdd(curC + d, 1); csrC[offC[d] + p] = sC[i];
    }
}

// ---------------- fused conv (3 graphs merged): agg + W + b + leaky + lw dot + lb ----
#define YA ((NSVC + 3) / 4)    // 500
#define YC ((NPOD + 3) / 4)    // 2000
#define YB ((NNODE + 3) / 4)   // 250
__global__ __launch_bounds__(256) void k_conv3(
    const float* __restrict__ feat_svc, const float* __restrict__ feat_pod,
    const float* __restrict__ feat_node,
    const float* __restrict__ w_svc, const float* __restrict__ b_svc,
    const float* __restrict__ lw_svc, const float* __restrict__ lb_svc,
    const float* __restrict__ w_ni, const float* __restrict__ b_ni,
    const float* __restrict__ lw_pod, const float* __restrict__ lb_pod,
    const float* __restrict__ w_in, const float* __restrict__ b_in,
    const float* __restrict__ lw_node, const float* __restrict__ lb_node,
    const float* ocA, const float* icA, const int* offA, const int* csrA,
    const float* ocC, const float* icC, const int* offC, const int* csrC,
    const float* ocB, const float* icB, const int* offB, const int* csrB,
    float* __restrict__ xseq)
{
    __shared__ float wl[FF * HH];
    __shared__ float bl[HH], lwl[HH];
    __shared__ float accs[4][FF];
    const int t = blockIdx.x;
    const int tid = threadIdx.x;
    int yb = blockIdx.y;
    const float *x, *w, *b, *lw, *lb, *oc, *ic; const int *off, *csr;
    int Ndst, rowofs;
    if (yb < YA) {
        x = feat_svc; w = w_svc; b = b_svc; lw = lw_svc; lb = lb_svc;
        oc = ocA; ic = icA; off = offA; csr = csrA; Ndst = NSVC; rowofs = 0;
    } else if (yb < YA + YC) {
        yb -= YA;
        x = feat_node; w = w_ni; b = b_ni; lw = lw_pod; lb = lb_pod;
        oc = ocC; ic = icC; off = offC; csr = csrC; Ndst = NPOD; rowofs = NSVC;
    } else {
        yb -= YA + YC;
        x = feat_pod; w = w_in; b = b_in; lw = lw_node; lb = lb_node;
        oc = ocB; ic = icB; off = offB; csr = csrB; Ndst = NNODE; rowofs = NSVC + NPOD;
    }
    for (int i = tid; i < FF * HH; i += 256) wl[i] = w[t * FF * HH + i];
    if (tid < HH) { bl[tid] = b[t * HH + tid]; lwl[tid] = lw[t * HH + tid]; }
    const int wv = tid >> 6, lane = tid & 63;
    const int dstn = yb * 4 + wv;
    __syncthreads();
    if (dstn < Ndst) {
        float a = 0.f;
        const int e0 = off[dstn], e1 = off[dstn + 1];
        const float* xb = x + (size_t)t * FF + lane;
        float xsP = 0.f, ocP = 1.f;
        if (e0 < e1) {
            int s0 = csr[e0];
            xsP = xb[(size_t)s0 * (TT * FF)]; ocP = oc[s0];
        }
        for (int i = e0; i < e1; ++i) {
            float xs = xsP, od = ocP;
            if (i + 1 < e1) {
                int s2 = csr[i + 1];
                xsP = xb[(size_t)s2 * (TT * FF)]; ocP = oc[s2];
            }
            a = fmaf(xs, rsqrtf(fmaxf(od, 1.f)), a);
        }
        a *= rsqrtf(fmaxf(ic[dstn], 1.f));
        accs[wv][lane] = a;
    }
    __syncthreads();
    if (dstn < Ndst) {
        float h0 = bl[lane], h1v = bl[64 + lane];
        #pragma unroll
        for (int f = 0; f < FF; ++f) {
            float af = accs[wv][f];
            h0  = fmaf(af, wl[f * HH + lane], h0);
            h1v = fmaf(af, wl[f * HH + 64 + lane], h1v);
        }
        h0  = (h0  >= 0.f) ? h0  : 0.01f * h0;
        h1v = (h1v >= 0.f) ? h1v : 0.01f * h1v;
        float p = h0 * lwl[lane] + h1v * lwl[64 + lane];
        #pragma unroll
        for (int o2 = 32; o2 >= 1; o2 >>= 1) p += __shfl_down(p, o2);
        if (lane == 0) xseq[(size_t)(rowofs + dstn) * TT + t] = p + lb[t];
    }
}

// X layout permutation: row r (gate-major g*128+j) is stored at column (j*4+g)
// so that lstm_rec lane tid = j*4+g reads X[n*512 + tid] coalesced.
__device__ __forceinline__ int xcol(int r) { return ((r & 127) << 2) | (r >> 7); }

// ---------------- input projection (layer 1): X = xin @ wih^T + (bih + bhh) --------
__global__ __launch_bounds__(256) void k_proj(
    const float* __restrict__ xin, int K,      // [N, K]
    const float* __restrict__ wih,             // [512, K]
    const float* __restrict__ bih, const float* __restrict__ bhh,
    float* __restrict__ Xout, int N)           // [N, 512] permuted cols
{
    __shared__ float xt[16 * 128];
    int n0 = blockIdx.x * 16, tid = threadIdx.x;
    for (int i = tid; i < 16 * K; i += 256) {
        int nn = i / K, kk = i - nn * K;
        int n = n0 + nn;
        xt[i] = (n < N) ? xin[(size_t)n * K + kk] : 0.f;
    }
    __syncthreads();
    float acc0[16], acc1[16];
    #pragma unroll
    for (int i = 0; i < 16; ++i) { acc0[i] = 0.f; acc1[i] = 0.f; }
    int r0 = tid, r1 = tid + 256;
    for (int k = 0; k < K; ++k) {
        float w0 = wih[(size_t)r0 * K + k];
        float w1 = wih[(size_t)r1 * K + k];
        #pragma unroll
        for (int i = 0; i < 16; ++i) {
            float xv = xt[i * K + k];
            acc0[i] = fmaf(xv, w0, acc0[i]);
            acc1[i] = fmaf(xv, w1, acc1[i]);
        }
    }
    float b0 = bih[r0] + bhh[r0], b1 = bih[r1] + bhh[r1];
    int c0 = xcol(r0), c1 = xcol(r1);
    for (int i = 0; i < 16; ++i) {
        int n = n0 + i;
        if (n < N) {
            Xout[(size_t)n * 512 + c0] = acc0[i] + b0;
            Xout[(size_t)n * 512 + c1] = acc1[i] + b1;
        }
    }
}

// ---------------- sequential LSTM recurrence (one block = one CU) ----------------
// thread = (j,g): unit j = tid>>2, gate g = tid&3. Each thread computes the FULL
// 128-deep dot product for its gate (4 independent 32-FMA chains) — no
// pre-activation reduction. h reads are wave-uniform (LDS broadcast). After the
// activation, 4 PARALLEL intra-quad shuffles deliver i,f,g,o to every lane;
// c,h computed redundantly in the 4 lanes. One lgkmcnt-only barrier per step.
__device__ void lstm_rec(const float* __restrict__ X, const float* __restrict__ Whh,
                         float* __restrict__ Hout, bool agent_x, bool agent_h,
                         int* wflag, int* sflag)
{
    __shared__ __align__(16) float hb0s[HH], hb1s[HH];
    const int tid = threadIdx.x;
    const int j = tid >> 2, g = tid & 3;
    const bool g0 = (g == 0);
    const int lbase = (tid & 63) & ~3;
    // full row (g*128 + j) of Whh in VGPRs
    float w[HH];
    {
        const float4* wr = reinterpret_cast<const float4*>(Whh + (size_t)(g * HH + j) * HH);
        #pragma unroll
        for (int k4 = 0; k4 < 32; ++k4) {
            float4 v = wr[k4];
            w[4*k4+0] = v.x; w[4*k4+1] = v.y; w[4*k4+2] = v.z; w[4*k4+3] = v.w;
        }
    }
    if (tid < HH) hb0s[tid] = 0.f;
    // activation constants: sigmoid (g=0,1,3): a = 1/(1+e^-s); tanh (g=2): a = 1-2/(1+e^2s)
    const float k1 = (g == 2) ? -2.f : 1.f;
    const float k2 = (g == 2) ? 2.f : -1.f;
    const float k3 = (g == 2) ? 1.f : 0.f;
    float c = 0.f;   // identical across each 4-lane quad
    __syncthreads();

    auto step = [&](const float* hsrc, float* hdst, float xc, float* ho) {
        const float4* hr = reinterpret_cast<const float4*>(hsrc);
        float s0 = 0.f, s1 = 0.f, s2 = 0.f, s3 = 0.f;
        #pragma unroll
        for (int q = 0; q < 8; ++q) {
            float4 h0 = hr[q], h1 = hr[8+q], h2 = hr[16+q], h3 = hr[24+q];
            s0 = fmaf(w[4*q+0],  h0.x, s0); s0 = fmaf(w[4*q+1],  h0.y, s0);
            s0 = fmaf(w[4*q+2],  h0.z, s0); s0 = fmaf(w[4*q+3],  h0.w, s0);
            s1 = fmaf(w[32+4*q+0], h1.x, s1); s1 = fmaf(w[32+4*q+1], h1.y, s1);
            s1 = fmaf(w[32+4*q+2], h1.z, s1); s1 = fmaf(w[32+4*q+3], h1.w, s1);
            s2 = fmaf(w[64+4*q+0], h2.x, s2); s2 = fmaf(w[64+4*q+1], h2.y, s2);
            s2 = fmaf(w[64+4*q+2], h2.z, s2); s2 = fmaf(w[64+4*q+3], h2.w, s2);
            s3 = fmaf(w[96+4*q+0], h3.x, s3); s3 = fmaf(w[96+4*q+1], h3.y, s3);
            s3 = fmaf(w[96+4*q+2], h3.z, s3); s3 = fmaf(w[96+4*q+3], h3.w, s3);
        }
        float sf = ((s0 + s1) + (s2 + s3)) + xc;
        float ev = __expf(k2 * sf);
        float a = fmaf(k1, __builtin_amdgcn_rcpf(1.f + ev), k3);
        // parallel intra-quad gather of the 4 gate activations
        float ai  = __shfl(a, lbase);
        float af_ = __shfl(a, lbase + 1);
        float agg = __shfl(a, lbase + 2);
        float ao_ = __shfl(a, lbase + 3);
        c = fmaf(af_, c, ai * agg);
        float e2 = __expf(2.f * c);
        float th = fmaf(-2.f, __builtin_amdgcn_rcpf(1.f + e2), 1.f);
        float hnew = ao_ * th;
        if (g0) {
            hdst[j] = hnew;
            if (agent_h) st_agent(ho, hnew); else *ho = hnew;
        }
        bar_fast();   // lgkmcnt only: global ops stay in flight
    };

    for (int ch = 0; ch < NCH; ++ch) {
        const int n0 = ch * CHK;
        const int n1 = (n0 + CHK < NTOT) ? (n0 + CHK) : NTOT;   // count always even
        if (wflag) {
            if (tid == 0) {
                while (__hip_atomic_load(wflag + ch, __ATOMIC_RELAXED, __HIP_MEMORY_SCOPE_AGENT) == 0)
                    __builtin_amdgcn_s_sleep(1);
            }
            __syncthreads();
            __threadfence();   // acquire
        }
        const float* xb = X + tid;
        float xc0 = agent_x ? ld_agent(xb + (size_t)n0 * 512) : xb[(size_t)n0 * 512];
        float xc1 = agent_x ? ld_agent(xb + (size_t)(n0+1) * 512) : xb[(size_t)(n0+1) * 512];
        for (int n = n0; n < n1; n += 2) {
            float xp2 = 0.f, xp3 = 0.f;
            if (n + 2 < n1) {
                const float* q2 = xb + (size_t)(n + 2) * 512;
                const float* q3 = xb + (size_t)(n + 3) * 512;
                xp2 = agent_x ? ld_agent(q2) : q2[0];
                xp3 = agent_x ? ld_agent(q3) : q3[0];
            }
            step(hb0s, hb1s, xc0, Hout + (size_t)n * HH + j);
            step(hb1s, hb0s, xc1, Hout + (size_t)(n + 1) * HH + j);
            xc0 = xp2; xc1 = xp3;
        }
        if (sflag) {
            __syncthreads();   // full drain: h stores visible before flag
            if (tid == 0)
                __hip_atomic_store(sflag + ch, 1, __ATOMIC_RELEASE, __HIP_MEMORY_SCOPE_AGENT);
        }
    }
}

// ---------------- layer-2 input projection worker (pipelined) ----------------
__device__ void proj_work(const float* __restrict__ h1, const float* __restrict__ Wih,
                          const float* __restrict__ bih, const float* __restrict__ bhh,
                          float* __restrict__ X2, int* wflag, int* sflag)
{
    __shared__ float hl[CHK * HH];     // 32 KB
    const int tid = threadIdx.x;       // row r of W_ih1 (gate-major)
    const float bsum = bih[tid] + bhh[tid];
    const int col = xcol(tid);
    const float4* wr = reinterpret_cast<const float4*>(Wih + (size_t)tid * HH);
    for (int ch = 0; ch < NCH; ++ch) {
        const int n0 = ch * CHK;
        const int cnt = (n0 + CHK < NTOT) ? CHK : (NTOT - n0);
        if (tid == 0) {
            while (__hip_atomic_load(wflag + ch, __ATOMIC_RELAXED, __HIP_MEMORY_SCOPE_AGENT) == 0)
                __builtin_amdgcn_s_sleep(1);
        }
        __syncthreads();
        __threadfence();
        for (int i = tid; i < cnt * HH; i += 512)
            hl[i] = ld_agent(h1 + (size_t)n0 * HH + i);
        __syncthreads();
        for (int t0 = 0; t0 < cnt; t0 += 16) {
            float acc[16];
            #pragma unroll
            for (int i = 0; i < 16; ++i) acc[i] = bsum;
            for (int k4 = 0; k4 < HH / 4; ++k4) {
                float4 wv = wr[k4];
                #pragma unroll
                for (int i = 0; i < 16; ++i) {
                    const float* hh = &hl[(t0 + i) * HH + 4 * k4];
                    acc[i] += wv.x*hh[0] + wv.y*hh[1] + wv.z*hh[2] + wv.w*hh[3];
                }
            }
            int tl = cnt - t0; if (tl > 16) tl = 16;
            for (int i = 0; i < tl; ++i)
                st_agent(X2 + (size_t)(n0 + t0 + i) * 512 + col, acc[i]);
        }
        __syncthreads();   // drain stores
        if (tid == 0)
            __hip_atomic_store(sflag + ch, 1, __ATOMIC_RELEASE, __HIP_MEMORY_SCOPE_AGENT);
    }
}

// ---------------- 3-stage pipeline: L1 rec -> proj -> L2 rec ----------------
__global__ __launch_bounds__(512, 2) void k_pipe(
    const float* __restrict__ X1, const float* __restrict__ w_hh0, float* __restrict__ h1,
    const float* __restrict__ w_ih1, const float* __restrict__ b_ih1, const float* __restrict__ b_hh1,
    float* __restrict__ X2, const float* __restrict__ w_hh1, float* __restrict__ out,
    int* flags1, int* flags2)
{
    if (blockIdx.x == 0)
        lstm_rec(X1, w_hh0, h1, false, true, nullptr, flags1);
    else if (blockIdx.x == 1)
        proj_work(h1, w_ih1, b_ih1, b_hh1, X2, flags1, flags2);
    else
        lstm_rec(X2, w_hh1, out, true, false, flags2, nullptr);
}

extern "C" void kernel_launch(void* const* d_in, const int* in_sizes, int n_in,
                              void* d_out, int out_size, void* d_ws, size_t ws_size,
                              hipStream_t stream) {
    const float* feat_svc = (const float*)d_in[0];
    const float* feat_pod = (const float*)d_in[1];
    const float* feat_node= (const float*)d_in[2];
    const float* w_svc = (const float*)d_in[3];
    const float* b_svc = (const float*)d_in[4];
    const float* w_in  = (const float*)d_in[5];
    const float* b_in  = (const float*)d_in[6];
    const float* w_ni  = (const float*)d_in[7];
    const float* b_ni  = (const float*)d_in[8];
    const float* lw_svc = (const float*)d_in[9];
    const float* lb_svc = (const float*)d_in[10];
    const float* lw_pod = (const float*)d_in[11];
    const float* lb_pod = (const float*)d_in[12];
    const float* lw_node= (const float*)d_in[13];
    const float* lb_node= (const float*)d_in[14];
    const float* w_ih0 = (const float*)d_in[15];
    const float* w_hh0 = (const float*)d_in[16];
    const float* b_ih0 = (const float*)d_in[17];
    const float* b_hh0 = (const float*)d_in[18];
    const float* w_ih1 = (const float*)d_in[19];
    const float* w_hh1 = (const float*)d_in[20];
    const float* b_ih1 = (const float*)d_in[21];
    const float* b_hh1 = (const float*)d_in[22];
    const int* eA_src = (const int*)d_in[23];   // svc -> svc
    const int* eA_dst = (const int*)d_in[24];
    const int* eB_src = (const int*)d_in[25];   // pod -> node
    const int* eB_dst = (const int*)d_in[26];
    const int* eC_src = (const int*)d_in[27];   // node -> pod
    const int* eC_dst = (const int*)d_in[28];

    float* ws = (float*)d_ws;
    // layout (4B units)
    float* ocA = ws + 0;        // 2000
    float* icA = ws + 2000;     // 2000
    float* ocB = ws + 4000;     // 8000 (pod out-deg)
    float* icB = ws + 12000;    // 1000 (node in-deg)
    float* ocC = ws + 13000;    // 1000 (node out-deg)
    float* icC = ws + 14000;    // 8000 (pod in-deg)
    int* curA = (int*)(ws + 22000);  // 2000
    int* curB = (int*)(ws + 24000);  // 1000
    int* curC = (int*)(ws + 25000);  // 8000
    int* offA = (int*)(ws + 33000);  // 2001
    int* offB = (int*)(ws + 35001);  // 1001
    int* offC = (int*)(ws + 36002);  // 8001
    int* sA   = (int*)(ws + 44003);  // 30000
    int* sB   = (int*)(ws + 74003);  // 24000
    int* sC   = (int*)(ws + 98003);  // 24000
    float* xseq = ws + 122003;       // 11000*32
    float* X1   = ws + 474003;       // 11000*512
    float* h1   = ws + 6106003;      // 11000*128
    int* flags1 = (int*)(ws + 7514003);   // NCH
    int* flags2 = flags1 + NCH;           // NCH
    float* X2   = X1;   // layer-2 proj overwrites X1 chunk-in-place (gated by flags1)

    // zero deg counts + cursors + pipeline flags
    hipMemsetAsync(d_ws, 0, 33000 * sizeof(float), stream);
    hipMemsetAsync(flags1, 0, 2 * NCH * sizeof(int), stream);

    k_count3<<<(ETOT + 255) / 256, 256, 0, stream>>>(
        eA_src, eA_dst, eB_src, eB_dst, eC_src, eC_dst,
        ocA, icA, ocB, icB, ocC, icC);

    k_scan<<<3, 256, 0, stream>>>(icA, NSVC, offA, icB, NNODE, offB, icC, NPOD, offC);

    k_scatter3<<<(ETOT + 255) / 256, 256, 0, stream>>>(
        eA_src, eA_dst, eB_src, eB_dst, eC_src, eC_dst,
        offA, curA, sA, offB, curB, sB, offC, curC, sC);

    // merged convs: A rows [0,2000), C rows [2000,10000), B rows [10000,11000)
    k_conv3<<<dim3(TT, YA + YC + YB), 256, 0, stream>>>(
        feat_svc, feat_pod, feat_node,
        w_svc, b_svc, lw_svc, lb_svc,
        w_ni, b_ni, lw_pod, lb_pod,
        w_in, b_in, lw_node, lb_node,
        ocA, icA, offA, sA,
        ocC, icC, offC, sC,
        ocB, icB, offB, sB,
        xseq);

    // layer-1 input projection (parallel GEMM, permuted X layout)
    k_proj<<<(NTOT + 15) / 16, 256, 0, stream>>>(xseq, TT, w_ih0, b_ih0, b_hh0, X1, NTOT);

    // 3-stage pipelined LSTM: L1 recurrence -> L2 proj -> L2 recurrence
    k_pipe<<<3, 512, 0, stream>>>(X1, w_hh0, h1, w_ih1, b_ih1, b_hh1,
                                  X2, w_hh1, (float*)d_out, flags1, flags2);
}

// Round 5
// 13290.218 us; speedup vs baseline: 1.0201x; 1.0201x over previous
//
#include <hip/hip_runtime.h>

#define NSVC 2000
#define NPOD 8000
#define NNODE 1000
#define NTOT 11000
#define TT 32
#define FF 64
#define HH 128
#define EA 30000
#define EB 24000
#define EC 24000
#define ETOT (EA + EB + EC)
#define CHK 64
#define NCH ((NTOT + CHK - 1) / CHK)   // 172

// ---------------- agent-scope helpers (cross-XCD safe) ----------------
__device__ __forceinline__ float ld_agent(const float* p) {
    return __hip_atomic_load(p, __ATOMIC_RELAXED, __HIP_MEMORY_SCOPE_AGENT);
}
__device__ __forceinline__ void st_agent(float* p, float v) {
    __hip_atomic_store(p, v, __ATOMIC_RELAXED, __HIP_MEMORY_SCOPE_AGENT);
}
// barrier that does NOT drain vmcnt (keeps global loads/stores in flight)
__device__ __forceinline__ void bar_fast() {
    asm volatile("s_waitcnt lgkmcnt(0)" ::: "memory");
    __builtin_amdgcn_s_barrier();
}
// DPP quad_perm: cross-lane within each 4-lane quad, plain-VALU latency.
// ctrl = lane pattern: xor1=0xB1 [1,0,3,2], xor2=0x4E [2,3,0,1],
// bcast q0..q3 = 0x00,0x55,0xAA,0xFF.
template<int CTRL>
__device__ __forceinline__ float qperm(float x) {
    return __int_as_float(__builtin_amdgcn_mov_dpp(__float_as_int(x), CTRL, 0xF, 0xF, false));
}

// ---------------- merged degree counting ----------------
__global__ void k_count3(const int* __restrict__ sA, const int* __restrict__ dA,
                         const int* __restrict__ sB, const int* __restrict__ dB,
                         const int* __restrict__ sC, const int* __restrict__ dC,
                         float* ocA, float* icA, float* ocB, float* icB,
                         float* ocC, float* icC) {
    int e = blockIdx.x * 256 + threadIdx.x;
    if (e < EA) {
        atomicAdd(ocA + sA[e], 1.f); atomicAdd(icA + dA[e], 1.f);
    } else if (e < EA + EB) {
        int i = e - EA;
        atomicAdd(ocB + sB[i], 1.f); atomicAdd(icB + dB[i], 1.f);
    } else if (e < ETOT) {
        int i = e - EA - EB;
        atomicAdd(ocC + sC[i], 1.f); atomicAdd(icC + dC[i], 1.f);
    }
}

// ---------------- prefix scan (3 graphs, one block each) ----------------
__global__ void k_scan(const float* cA, int nA, int* oA,
                       const float* cB, int nB, int* oB,
                       const float* cC, int nC, int* oC) {
    const float* c; int n; int* o;
    if (blockIdx.x == 0)      { c = cA; n = nA; o = oA; }
    else if (blockIdx.x == 1) { c = cB; n = nB; o = oB; }
    else                      { c = cC; n = nC; o = oC; }
    __shared__ int s[256];
    __shared__ int carry;
    int tid = threadIdx.x;
    if (tid == 0) { carry = 0; o[0] = 0; }
    __syncthreads();
    for (int base = 0; base < n; base += 256) {
        int idx = base + tid;
        int v = (idx < n) ? (int)c[idx] : 0;
        s[tid] = v;
        __syncthreads();
        for (int d = 1; d < 256; d <<= 1) {
            int t = (tid >= d) ? s[tid - d] : 0;
            __syncthreads();
            s[tid] += t;
            __syncthreads();
        }
        if (idx < n) o[idx + 1] = carry + s[tid];
        __syncthreads();
        if (tid == 255) carry += s[255];
        __syncthreads();
    }
}

// ---------------- merged CSR scatter ----------------
__global__ void k_scatter3(const int* __restrict__ sA, const int* __restrict__ dA,
                           const int* __restrict__ sB, const int* __restrict__ dB,
                           const int* __restrict__ sC, const int* __restrict__ dC,
                           const int* offA, int* curA, int* csrA,
                           const int* offB, int* curB, int* csrB,
                           const int* offC, int* curC, int* csrC) {
    int e = blockIdx.x * 256 + threadIdx.x;
    if (e < EA) {
        int d = dA[e]; int p = atomicAdd(curA + d, 1); csrA[offA[d] + p] = sA[e];
    } else if (e < EA + EB) {
        int i = e - EA;
        int d = dB[i]; int p = atomicAdd(curB + d, 1); csrB[offB[d] + p] = sB[i];
    } else if (e < ETOT) {
        int i = e - EA - EB;
        int d = dC[i]; int p = atomicAdd(curC + d, 1); csrC[offC[d] + p] = sC[i];
    }
}

// ---------------- fused conv (3 graphs merged, 16 dst/block): ----------------
#define YA16 ((NSVC + 15) / 16)    // 125
#define YC16 ((NPOD + 15) / 16)    // 500
#define YB16 ((NNODE + 15) / 16)   // 63
__global__ __launch_bounds__(256) void k_conv3(
    const float* __restrict__ feat_svc, const float* __restrict__ feat_pod,
    const float* __restrict__ feat_node,
    const float* __restrict__ w_svc, const float* __restrict__ b_svc,
    const float* __restrict__ lw_svc, const float* __restrict__ lb_svc,
    const float* __restrict__ w_ni, const float* __restrict__ b_ni,
    const float* __restrict__ lw_pod, const float* __restrict__ lb_pod,
    const float* __restrict__ w_in, const float* __restrict__ b_in,
    const float* __restrict__ lw_node, const float* __restrict__ lb_node,
    const float* ocA, const float* icA, const int* offA, const int* csrA,
    const float* ocC, const float* icC, const int* offC, const int* csrC,
    const float* ocB, const float* icB, const int* offB, const int* csrB,
    float* __restrict__ xseq)
{
    __shared__ float wl[FF * HH];
    __shared__ float bl[HH], lwl[HH];
    __shared__ float accs[4][FF];
    const int t = blockIdx.x;
    const int tid = threadIdx.x;
    int yb = blockIdx.y;
    const float *x, *w, *b, *lw, *lb, *oc, *ic; const int *off, *csr;
    int Ndst, rowofs;
    if (yb < YA16) {
        x = feat_svc; w = w_svc; b = b_svc; lw = lw_svc; lb = lb_svc;
        oc = ocA; ic = icA; off = offA; csr = csrA; Ndst = NSVC; rowofs = 0;
    } else if (yb < YA16 + YC16) {
        yb -= YA16;
        x = feat_node; w = w_ni; b = b_ni; lw = lw_pod; lb = lb_pod;
        oc = ocC; ic = icC; off = offC; csr = csrC; Ndst = NPOD; rowofs = NSVC;
    } else {
        yb -= YA16 + YC16;
        x = feat_pod; w = w_in; b = b_in; lw = lw_node; lb = lb_node;
        oc = ocB; ic = icB; off = offB; csr = csrB; Ndst = NNODE; rowofs = NSVC + NPOD;
    }
    for (int i = tid; i < FF * HH; i += 256) wl[i] = w[t * FF * HH + i];
    if (tid < HH) { bl[tid] = b[t * HH + tid]; lwl[tid] = lw[t * HH + tid]; }
    const int wv = tid >> 6, lane = tid & 63;
    __syncthreads();
    for (int sub = 0; sub < 4; ++sub) {
        const int dstn = yb * 16 + sub * 4 + wv;
        if (dstn < Ndst) {
            float a = 0.f;
            const int e0 = off[dstn], e1 = off[dstn + 1];
            const float* xb = x + (size_t)t * FF + lane;
            float xsP = 0.f, ocP = 1.f;
            if (e0 < e1) {
                int s0 = csr[e0];
                xsP = xb[(size_t)s0 * (TT * FF)]; ocP = oc[s0];
            }
            for (int i = e0; i < e1; ++i) {
                float xs = xsP, od = ocP;
                if (i + 1 < e1) {
                    int s2 = csr[i + 1];
                    xsP = xb[(size_t)s2 * (TT * FF)]; ocP = oc[s2];
                }
                a = fmaf(xs, rsqrtf(fmaxf(od, 1.f)), a);
            }
            a *= rsqrtf(fmaxf(ic[dstn], 1.f));
            accs[wv][lane] = a;     // wave-local: write then read by same wave
            float h0 = bl[lane], h1v = bl[64 + lane];
            #pragma unroll
            for (int f = 0; f < FF; ++f) {
                float af = accs[wv][f];
                h0  = fmaf(af, wl[f * HH + lane], h0);
                h1v = fmaf(af, wl[f * HH + 64 + lane], h1v);
            }
            h0  = (h0  >= 0.f) ? h0  : 0.01f * h0;
            h1v = (h1v >= 0.f) ? h1v : 0.01f * h1v;
            float p = h0 * lwl[lane] + h1v * lwl[64 + lane];
            #pragma unroll
            for (int o2 = 32; o2 >= 1; o2 >>= 1) p += __shfl_down(p, o2);
            if (lane == 0) xseq[(size_t)(rowofs + dstn) * TT + t] = p + lb[t];
        }
    }
}

// X layout permutation: row r (gate-major g*128+j) stored at column (j*4+g),
// so lstm_rec lane tid = 4j+p reads X[n*512 + tid] coalesced (lane p owns gate p).
__device__ __forceinline__ int xcol(int r) { return ((r & 127) << 2) | (r >> 7); }

// ---------------- input projection (layer 1): X = xin @ wih^T + (bih + bhh) --------
__global__ __launch_bounds__(256) void k_proj(
    const float* __restrict__ xin, int K,      // [N, K]
    const float* __restrict__ wih,             // [512, K]
    const float* __restrict__ bih, const float* __restrict__ bhh,
    float* __restrict__ Xout, int N)           // [N, 512] permuted cols
{
    __shared__ float xt[16 * 128];
    int n0 = blockIdx.x * 16, tid = threadIdx.x;
    for (int i = tid; i < 16 * K; i += 256) {
        int nn = i / K, kk = i - nn * K;
        int n = n0 + nn;
        xt[i] = (n < N) ? xin[(size_t)n * K + kk] : 0.f;
    }
    __syncthreads();
    float acc0[16], acc1[16];
    #pragma unroll
    for (int i = 0; i < 16; ++i) { acc0[i] = 0.f; acc1[i] = 0.f; }
    int r0 = tid, r1 = tid + 256;
    for (int k = 0; k < K; ++k) {
        float w0 = wih[(size_t)r0 * K + k];
        float w1 = wih[(size_t)r1 * K + k];
        #pragma unroll
        for (int i = 0; i < 16; ++i) {
            float xv = xt[i * K + k];
            acc0[i] = fmaf(xv, w0, acc0[i]);
            acc1[i] = fmaf(xv, w1, acc1[i]);
        }
    }
    float b0 = bih[r0] + bhh[r0], b1 = bih[r1] + bhh[r1];
    int c0 = xcol(r0), c1 = xcol(r1);
    for (int i = 0; i < 16; ++i) {
        int n = n0 + i;
        if (n < N) {
            Xout[(size_t)n * 512 + c0] = acc0[i] + b0;
            Xout[(size_t)n * 512 + c1] = acc1[i] + b1;
        }
    }
}

// ---------------- sequential LSTM recurrence (one block = one CU) ----------------
// thread = (j,p): unit j = tid>>2, k-chunk p = tid&3 (traffic-optimal G=4 mapping:
// each thread computes all 4 gate partials over its 32-k slice, reads 32 h).
// ALL cross-lane traffic is intra-quad -> DPP quad_perm (VALU, no LDS latency):
// reduce-scatter depth 2 (lane p ends with gate p total), activation, 4 quad
// broadcasts, redundant c in all 4 lanes. One lgkmcnt-only barrier per step.
__device__ void lstm_rec(const float* __restrict__ X, const float* __restrict__ Whh,
                         float* __restrict__ Hout, bool agent_x, bool agent_h,
                         int* wflag, int* sflag)
{
    __shared__ __align__(16) float hb[2][4 * 36];   // padded stride 36: conflict-free
    const int tid = threadIdx.x;
    const int j = tid >> 2, p = tid & 3;
    float w[4][32];
    #pragma unroll
    for (int g = 0; g < 4; ++g) {
        const float4* wr = reinterpret_cast<const float4*>(Whh + (size_t)(g * HH + j) * HH + p * 32);
        #pragma unroll
        for (int k4 = 0; k4 < 8; ++k4) {
            float4 v = wr[k4];
            w[g][4*k4+0] = v.x; w[g][4*k4+1] = v.y;
            w[g][4*k4+2] = v.z; w[g][4*k4+3] = v.w;
        }
    }
    if (tid < HH) hb[0][(tid >> 5) * 36 + (tid & 31)] = 0.f;
    // sigmoid (p=0,1,3): a = 1/(1+e^-s); tanh (p=2): a = 1 - 2/(1+e^2s)
    const float k1 = (p == 2) ? -2.f : 1.f;
    const float k2 = (p == 2) ? 2.f : -1.f;
    const float k3 = (p == 2) ? 1.f : 0.f;
    const bool pa = (p & 1) != 0, pb = (p & 2) != 0;
    float c = 0.f;   // identical across each 4-lane quad
    __syncthreads();

    auto step = [&](const float* hsrc, float* hdst, float xc, float* ho) {
        const float4* hr = reinterpret_cast<const float4*>(hsrc + p * 36);
        float h[32];
        #pragma unroll
        for (int k4 = 0; k4 < 8; ++k4) {
            float4 v4 = hr[k4];
            h[4*k4+0] = v4.x; h[4*k4+1] = v4.y;
            h[4*k4+2] = v4.z; h[4*k4+3] = v4.w;
        }
        float s0a=0.f,s1a=0.f,s2a=0.f,s3a=0.f,s0b=0.f,s1b=0.f,s2b=0.f,s3b=0.f;
        #pragma unroll
        for (int k = 0; k < 16; ++k) {
            float hv = h[k], hw = h[16 + k];
            s0a = fmaf(w[0][k], hv, s0a); s0b = fmaf(w[0][16+k], hw, s0b);
            s1a = fmaf(w[1][k], hv, s1a); s1b = fmaf(w[1][16+k], hw, s1b);
            s2a = fmaf(w[2][k], hv, s2a); s2b = fmaf(w[2][16+k], hw, s2b);
            s3a = fmaf(w[3][k], hv, s3a); s3b = fmaf(w[3][16+k], hw, s3b);
        }
        float s0 = s0a + s0b, s1 = s1a + s1b, s2 = s2a + s2b, s3 = s3a + s3b;
        // DPP reduce-scatter over the quad: lane p ends with gate p's total
        float zA = pa ? s0 : s1;
        float u  = (pa ? s1 : s0) + qperm<0xB1>(zA);
        float zB = pa ? s2 : s3;
        float v  = (pa ? s3 : s2) + qperm<0xB1>(zB);
        float zC = pb ? u : v;
        float sf = ((pb ? v : u) + qperm<0x4E>(zC)) + xc;
        // one activation per lane
        float ev = __expf(k2 * sf);
        float a  = fmaf(k1, __builtin_amdgcn_rcpf(1.f + ev), k3);
        // quad broadcasts: i,f,g,o to every lane
        float ai = qperm<0x00>(a);
        float af = qperm<0x55>(a);
        float ag = qperm<0xAA>(a);
        float ao = qperm<0xFF>(a);
        c = fmaf(af, c, ai * ag);
        float e2 = __expf(2.f * c);
        float th = fmaf(-2.f, __builtin_amdgcn_rcpf(1.f + e2), 1.f);
        float hnew = ao * th;
        if (p == 0) {
            hdst[(j >> 5) * 36 + (j & 31)] = hnew;
            if (agent_h) st_agent(ho, hnew); else *ho = hnew;
        }
        bar_fast();   // lgkmcnt only: global ops stay in flight
    };

    for (int ch = 0; ch < NCH; ++ch) {
        const int n0 = ch * CHK;
        const int n1 = (n0 + CHK < NTOT) ? (n0 + CHK) : NTOT;   // count always even
        if (wflag) {
            if (tid == 0) {
                while (__hip_atomic_load(wflag + ch, __ATOMIC_RELAXED, __HIP_MEMORY_SCOPE_AGENT) == 0)
                    __builtin_amdgcn_s_sleep(1);
            }
            __syncthreads();
            __threadfence();   // acquire
        }
        const float* xb = X + tid;    // coalesced (xcol-permuted layout)
        float xc0 = agent_x ? ld_agent(xb + (size_t)n0 * 512) : xb[(size_t)n0 * 512];
        float xc1 = agent_x ? ld_agent(xb + (size_t)(n0+1) * 512) : xb[(size_t)(n0+1) * 512];
        for (int n = n0; n < n1; n += 2) {
            float xp2 = 0.f, xp3 = 0.f;
            if (n + 2 < n1) {
                const float* q2 = xb + (size_t)(n + 2) * 512;
                const float* q3 = xb + (size_t)(n + 3) * 512;
                xp2 = agent_x ? ld_agent(q2) : q2[0];
                xp3 = agent_x ? ld_agent(q3) : q3[0];
            }
            step(hb[0], hb[1], xc0, Hout + (size_t)n * HH + j);
            step(hb[1], hb[0], xc1, Hout + (size_t)(n + 1) * HH + j);
            xc0 = xp2; xc1 = xp3;
        }
        if (sflag) {
            __syncthreads();   // full drain: h stores visible before flag
            if (tid == 0)
                __hip_atomic_store(sflag + ch, 1, __ATOMIC_RELEASE, __HIP_MEMORY_SCOPE_AGENT);
        }
    }
}

// ---------------- layer-2 input projection worker (pipelined) ----------------
__device__ void proj_work(const float* __restrict__ h1, const float* __restrict__ Wih,
                          const float* __restrict__ bih, const float* __restrict__ bhh,
                          float* __restrict__ X2, int* wflag, int* sflag)
{
    __shared__ float hl[CHK * HH];     // 32 KB
    const int tid = threadIdx.x;       // row r of W_ih1 (gate-major)
    const float bsum = bih[tid] + bhh[tid];
    const int col = xcol(tid);
    const float4* wr = reinterpret_cast<const float4*>(Wih + (size_t)tid * HH);
    for (int ch = 0; ch < NCH; ++ch) {
        const int n0 = ch * CHK;
        const int cnt = (n0 + CHK < NTOT) ? CHK : (NTOT - n0);
        if (tid == 0) {
            while (__hip_atomic_load(wflag + ch, __ATOMIC_RELAXED, __HIP_MEMORY_SCOPE_AGENT) == 0)
                __builtin_amdgcn_s_sleep(1);
        }
        __syncthreads();
        __threadfence();
        for (int i = tid; i < cnt * HH; i += 512)
            hl[i] = ld_agent(h1 + (size_t)n0 * HH + i);
        __syncthreads();
        for (int t0 = 0; t0 < cnt; t0 += 16) {
            float acc[16];
            #pragma unroll
            for (int i = 0; i < 16; ++i) acc[i] = bsum;
            for (int k4 = 0; k4 < HH / 4; ++k4) {
                float4 wv = wr[k4];
                #pragma unroll
                for (int i = 0; i < 16; ++i) {
                    const float* hh = &hl[(t0 + i) * HH + 4 * k4];
                    acc[i] += wv.x*hh[0] + wv.y*hh[1] + wv.z*hh[2] + wv.w*hh[3];
                }
            }
            int tl = cnt - t0; if (tl > 16) tl = 16;
            for (int i = 0; i < tl; ++i)
                st_agent(X2 + (size_t)(n0 + t0 + i) * 512 + col, acc[i]);
        }
        __syncthreads();   // drain stores
        if (tid == 0)
            __hip_atomic_store(sflag + ch, 1, __ATOMIC_RELEASE, __HIP_MEMORY_SCOPE_AGENT);
    }
}

// ---------------- 3-stage pipeline: L1 rec -> proj -> L2 rec ----------------
__global__ __launch_bounds__(512, 2) void k_pipe(
    const float* __restrict__ X1, const float* __restrict__ w_hh0, float* __restrict__ h1,
    const float* __restrict__ w_ih1, const float* __restrict__ b_ih1, const float* __restrict__ b_hh1,
    float* __restrict__ X2, const float* __restrict__ w_hh1, float* __restrict__ out,
    int* flags1, int* flags2)
{
    if (blockIdx.x == 0)
        lstm_rec(X1, w_hh0, h1, false, true, nullptr, flags1);
    else if (blockIdx.x == 1)
        proj_work(h1, w_ih1, b_ih1, b_hh1, X2, flags1, flags2);
    else
        lstm_rec(X2, w_hh1, out, true, false, flags2, nullptr);
}

extern "C" void kernel_launch(void* const* d_in, const int* in_sizes, int n_in,
                              void* d_out, int out_size, void* d_ws, size_t ws_size,
                              hipStream_t stream) {
    const float* feat_svc = (const float*)d_in[0];
    const float* feat_pod = (const float*)d_in[1];
    const float* feat_node= (const float*)d_in[2];
    const float* w_svc = (const float*)d_in[3];
    const float* b_svc = (const float*)d_in[4];
    const float* w_in  = (const float*)d_in[5];
    const float* b_in  = (const float*)d_in[6];
    const float* w_ni  = (const float*)d_in[7];
    const float* b_ni  = (const float*)d_in[8];
    const float* lw_svc = (const float*)d_in[9];
    const float* lb_svc = (const float*)d_in[10];
    const float* lw_pod = (const float*)d_in[11];
    const float* lb_pod = (const float*)d_in[12];
    const float* lw_node= (const float*)d_in[13];
    const float* lb_node= (const float*)d_in[14];
    const float* w_ih0 = (const float*)d_in[15];
    const float* w_hh0 = (const float*)d_in[16];
    const float* b_ih0 = (const float*)d_in[17];
    const float* b_hh0 = (const float*)d_in[18];
    const float* w_ih1 = (const float*)d_in[19];
    const float* w_hh1 = (const float*)d_in[20];
    const float* b_ih1 = (const float*)d_in[21];
    const float* b_hh1 = (const float*)d_in[22];
    const int* eA_src = (const int*)d_in[23];   // svc -> svc
    const int* eA_dst = (const int*)d_in[24];
    const int* eB_src = (const int*)d_in[25];   // pod -> node
    const int* eB_dst = (const int*)d_in[26];
    const int* eC_src = (const int*)d_in[27];   // node -> pod
    const int* eC_dst = (const int*)d_in[28];

    float* ws = (float*)d_ws;
    // layout (4B units)
    float* ocA = ws + 0;        // 2000
    float* icA = ws + 2000;     // 2000
    float* ocB = ws + 4000;     // 8000 (pod out-deg)
    float* icB = ws + 12000;    // 1000 (node in-deg)
    float* ocC = ws + 13000;    // 1000 (node out-deg)
    float* icC = ws + 14000;    // 8000 (pod in-deg)
    int* curA = (int*)(ws + 22000);  // 2000
    int* curB = (int*)(ws + 24000);  // 1000
    int* curC = (int*)(ws + 25000);  // 8000
    int* offA = (int*)(ws + 33000);  // 2001
    int* offB = (int*)(ws + 35001);  // 1001
    int* offC = (int*)(ws + 36002);  // 8001
    int* sA   = (int*)(ws + 44003);  // 30000
    int* sB   = (int*)(ws + 74003);  // 24000
    int* sC   = (int*)(ws + 98003);  // 24000
    float* xseq = ws + 122003;       // 11000*32
    float* X1   = ws + 474003;       // 11000*512
    float* h1   = ws + 6106003;      // 11000*128
    int* flags1 = (int*)(ws + 7514003);   // NCH
    int* flags2 = flags1 + NCH;           // NCH
    float* X2   = X1;   // layer-2 proj overwrites X1 chunk-in-place (gated by flags1)

    // zero deg counts + cursors + pipeline flags
    hipMemsetAsync(d_ws, 0, 33000 * sizeof(float), stream);
    hipMemsetAsync(flags1, 0, 2 * NCH * sizeof(int), stream);

    k_count3<<<(ETOT + 255) / 256, 256, 0, stream>>>(
        eA_src, eA_dst, eB_src, eB_dst, eC_src, eC_dst,
        ocA, icA, ocB, icB, ocC, icC);

    k_scan<<<3, 256, 0, stream>>>(icA, NSVC, offA, icB, NNODE, offB, icC, NPOD, offC);

    k_scatter3<<<(ETOT + 255) / 256, 256, 0, stream>>>(
        eA_src, eA_dst, eB_src, eB_dst, eC_src, eC_dst,
        offA, curA, sA, offB, curB, sB, offC, curC, sC);

    // merged convs: A rows [0,2000), C rows [2000,10000), B rows [10000,11000)
    k_conv3<<<dim3(TT, YA16 + YC16 + YB16), 256, 0, stream>>>(
        feat_svc, feat_pod, feat_node,
        w_svc, b_svc, lw_svc, lb_svc,
        w_ni, b_ni, lw_pod, lb_pod,
        w_in, b_in, lw_node, lb_node,
        ocA, icA, offA, sA,
        ocC, icC, offC, sC,
        ocB, icB, offB, sB,
        xseq);

    // layer-1 input projection (parallel GEMM, permuted X layout)
    k_proj<<<(NTOT + 15) / 16, 256, 0, stream>>>(xseq, TT, w_ih0, b_ih0, b_hh0, X1, NTOT);

    // 3-stage pipelined LSTM: L1 recurrence -> L2 proj -> L2 recurrence
    k_pipe<<<3, 512, 0, stream>>>(X1, w_hh0, h1, w_ih1, b_ih1, b_hh1,
                                  X2, w_hh1, (float*)d_out, flags1, flags2);
}